// Round 8
// baseline (209.921 us; speedup 1.0000x reference)
//
#include <hip/hip_runtime.h>

#define N_NODES 100000
#define DIM 64
#define N_EDGES 1250000
#define EPS 1e-12f

#define NREP 8                                  // histogram replicas
#define NODES_PER_BLK 256
#define NB2 ((N_NODES + NODES_PER_BLK - 1) / NODES_PER_BLK)   // 391 scan blocks

typedef unsigned short ushort8 __attribute__((ext_vector_type(8)));

__device__ inline unsigned short f2bf(float f) {   // fp32 -> bf16 RNE
    unsigned int u = __float_as_uint(f);
    return (unsigned short)((u + 0x7FFFu + ((u >> 16) & 1u)) >> 16);
}
__device__ inline float bf2f(unsigned short h) {
    return __uint_as_float(((unsigned int)h) << 16);
}

// ---- Pass 0: x (fp32) -> xh (bf16); halves gather traffic ----
__global__ void convert_kernel(const float4* __restrict__ x4,
                               ushort8* __restrict__ xh8) {
    int i = blockIdx.x * blockDim.x + threadIdx.x;
    if (i < N_NODES * DIM / 8) {
        float4 a = x4[2 * i];
        float4 b = x4[2 * i + 1];
        ushort8 o;
        o[0] = f2bf(a.x); o[1] = f2bf(a.y); o[2] = f2bf(a.z); o[3] = f2bf(a.w);
        o[4] = f2bf(b.x); o[5] = f2bf(b.y); o[6] = f2bf(b.z); o[7] = f2bf(b.w);
        xh8[i] = o;
    }
}

// ---- Pass 1: 8-way replicated histogram + per-replica rank.
// degA is replica-major: replica r's bins are 400 KB apart, breaking
// per-cache-line serialization of the returning atomics.
__global__ void hist_rank_kernel(const int* __restrict__ dst,
                                 int* __restrict__ degA,
                                 unsigned short* __restrict__ rank) {
    int e = blockIdx.x * blockDim.x + threadIdx.x;
    if (e < N_EDGES) {
        int r = e & (NREP - 1);
        rank[e] = (unsigned short)atomicAdd(&degA[r * N_NODES + dst[e]], 1);
    }
}

// ---- Pass 2a: scan with built-in transpose. Thread t owns node
// d = blk*256+t: reads its 8 replica counts (coalesced streams), scans the
// block's 256 node-totals in LDS, writes node-major sub-segment bases
// row8[d*8+r] (int4 x2, coalesced) + deg_total[d]; bsums[blk] = block total.
__global__ void scan_nodes_kernel(const int* __restrict__ degA,
                                  int* __restrict__ row8,
                                  int* __restrict__ deg_total,
                                  int* __restrict__ bsums) {
    __shared__ int lds[NODES_PER_BLK];
    int t = threadIdx.x;
    int d = blockIdx.x * NODES_PER_BLK + t;

    int c[NREP];
    int sum = 0;
    #pragma unroll
    for (int r = 0; r < NREP; ++r) {
        c[r] = (d < N_NODES) ? degA[r * N_NODES + d] : 0;
        sum += c[r];
    }
    lds[t] = sum;
    __syncthreads();
    for (int off = 1; off < NODES_PER_BLK; off <<= 1) {
        int val = lds[t];
        int add = (t >= off) ? lds[t - off] : 0;
        __syncthreads();
        lds[t] = val + add;
        __syncthreads();
    }
    int run = (t > 0) ? lds[t - 1] : 0;        // block-local exclusive prefix
    if (t == NODES_PER_BLK - 1) bsums[blockIdx.x] = lds[NODES_PER_BLK - 1];
    if (d < N_NODES) {
        int4 lo, hi;
        lo.x = run; run += c[0];
        lo.y = run; run += c[1];
        lo.z = run; run += c[2];
        lo.w = run; run += c[3];
        hi.x = run; run += c[4];
        hi.y = run; run += c[5];
        hi.z = run; run += c[6];
        hi.w = run; run += c[7];
        ((int4*)row8)[d * 2]     = lo;
        ((int4*)row8)[d * 2 + 1] = hi;
        deg_total[d] = sum;
    }
}

// ---- Pass 2b: exclusive scan of the 391 block sums (single 512-wide block);
// consumers add bsums[d>>8] on the fly.
__global__ void scan_bsums_kernel(int* __restrict__ bsums) {
    __shared__ int lds[512];
    int t = threadIdx.x;
    lds[t] = (t < NB2) ? bsums[t] : 0;
    __syncthreads();
    for (int off = 1; off < 512; off <<= 1) {
        int val = lds[t];
        int add = (t >= off) ? lds[t - off] : 0;
        __syncthreads();
        lds[t] = val + add;
        __syncthreads();
    }
    int excl = (t > 0) ? lds[t - 1] : 0;
    if (t < NB2) bsums[t] = excl;
}

// ---- Pass 3: scatter fill — no atomics; ONE scattered read (row8) ----
__global__ void fill_adj_kernel(const int* __restrict__ src,
                                const int* __restrict__ dst,
                                const unsigned short* __restrict__ rank,
                                const int* __restrict__ row8,
                                const int* __restrict__ bsums,
                                int* __restrict__ adj) {
    int e = blockIdx.x * blockDim.x + threadIdx.x;
    if (e < N_EDGES) {
        int d = dst[e];
        int r = e & (NREP - 1);
        int pos = row8[d * NREP + r] + bsums[d >> 8] + (int)rank[e];
        adj[pos] = src[e];
    }
}

// ---- Pass 4: fused gather-mean (bf16 rows) + L2-normalize + relu(2h) ----
// One wave per node: 8 row-slots (g) x 8 chunks (sub); fp32 accumulation.
__global__ void aggregate_kernel(const ushort8* __restrict__ xh8,
                                 const int* __restrict__ row8,
                                 const int* __restrict__ bsums,
                                 const int* __restrict__ deg_total,
                                 const int* __restrict__ adj,
                                 float* __restrict__ out) {
    int node = blockIdx.x * (blockDim.x >> 6) + (threadIdx.x >> 6);
    if (node >= N_NODES) return;
    int lane = threadIdx.x & 63;
    int g    = lane >> 3;   // row slot 0..7
    int sub  = lane & 7;    // ushort8 chunk within row

    int start = row8[node * NREP] + bsums[node >> 8];
    int degn  = deg_total[node];

    float acc[8] = {0.f, 0.f, 0.f, 0.f, 0.f, 0.f, 0.f, 0.f};

    int e = g;
    for (; e + 8 < degn; e += 16) {
        int s0 = adj[start + e];
        int s1 = adj[start + e + 8];
        ushort8 v0 = xh8[(size_t)s0 * 8 + sub];
        ushort8 v1 = xh8[(size_t)s1 * 8 + sub];
        #pragma unroll
        for (int k = 0; k < 8; ++k) acc[k] += bf2f(v0[k]) + bf2f(v1[k]);
    }
    if (e < degn) {
        int s0 = adj[start + e];
        ushort8 v0 = xh8[(size_t)s0 * 8 + sub];
        #pragma unroll
        for (int k = 0; k < 8; ++k) acc[k] += bf2f(v0[k]);
    }

    #pragma unroll
    for (int off = 8; off < 64; off <<= 1) {
        #pragma unroll
        for (int k = 0; k < 8; ++k) acc[k] += __shfl_xor(acc[k], off, 64);
    }

    float inv = 1.0f / fmaxf((float)degn, 1.0f);
    #pragma unroll
    for (int k = 0; k < 8; ++k) acc[k] *= inv;

    float ss = 0.f;
    #pragma unroll
    for (int k = 0; k < 8; ++k) ss += acc[k] * acc[k];
    #pragma unroll
    for (int off = 1; off < 8; off <<= 1) ss += __shfl_xor(ss, off, 64);

    float scale = 2.0f / fmaxf(sqrtf(ss), EPS);
    if (g == 0) {
        float4 o0, o1;
        o0.x = fmaxf(acc[0] * scale, 0.0f); o0.y = fmaxf(acc[1] * scale, 0.0f);
        o0.z = fmaxf(acc[2] * scale, 0.0f); o0.w = fmaxf(acc[3] * scale, 0.0f);
        o1.x = fmaxf(acc[4] * scale, 0.0f); o1.y = fmaxf(acc[5] * scale, 0.0f);
        o1.z = fmaxf(acc[6] * scale, 0.0f); o1.w = fmaxf(acc[7] * scale, 0.0f);
        ((float4*)out)[(size_t)node * 16 + 2 * sub]     = o0;
        ((float4*)out)[(size_t)node * 16 + 2 * sub + 1] = o1;
    }
}

extern "C" void kernel_launch(void* const* d_in, const int* in_sizes, int n_in,
                              void* d_out, int out_size, void* d_ws, size_t ws_size,
                              hipStream_t stream) {
    const float* x  = (const float*)d_in[0];
    const int*   ei = (const int*)d_in[1];
    float* out = (float*)d_out;

    const int* src = ei;
    const int* dst = ei + N_EDGES;

    // ws: xh[12.8MB] | degA[8N=3.2MB] | row8[8N=3.2MB] | deg_total[N] |
    //     bsums[512] | rank[E ushort=2.5MB] | adj[E=5MB]  (~27.2 MB)
    ushort8* xh    = (ushort8*)d_ws;
    int* degA      = (int*)((char*)d_ws + (size_t)N_NODES * DIM * 2);
    int* row8      = degA + NREP * N_NODES;
    int* deg_total = row8 + NREP * N_NODES;
    int* bsums     = deg_total + N_NODES;
    unsigned short* rank = (unsigned short*)(bsums + 512);
    int* adj       = (int*)(rank + N_EDGES);

    hipMemsetAsync(degA, 0, (size_t)NREP * N_NODES * sizeof(int), stream);

    int cvb = (N_NODES * DIM / 8 + 255) / 256;
    convert_kernel<<<cvb, 256, 0, stream>>>((const float4*)x, xh);

    int eb = (N_EDGES + 255) / 256;
    hist_rank_kernel<<<eb, 256, 0, stream>>>(dst, degA, rank);

    scan_nodes_kernel<<<NB2, NODES_PER_BLK, 0, stream>>>(degA, row8, deg_total,
                                                         bsums);
    scan_bsums_kernel<<<1, 512, 0, stream>>>(bsums);

    fill_adj_kernel<<<eb, 256, 0, stream>>>(src, dst, rank, row8, bsums, adj);

    int waves_per_block = 256 / 64;
    int agg_blocks = (N_NODES + waves_per_block - 1) / waves_per_block;
    aggregate_kernel<<<agg_blocks, 256, 0, stream>>>(xh, row8, bsums, deg_total,
                                                     adj, out);
}